// Round 6
// baseline (261.426 us; speedup 1.0000x reference)
//
#include <hip/hip_runtime.h>

#define SEQ 128
#define BATCH 512
#define IN_DIM 128
#define HID 128

typedef float vf2 __attribute__((ext_vector_type(2)));

__device__ __forceinline__ float sigmoid_f(float x) { return 1.0f / (1.0f + __expf(-x)); }
__device__ __forceinline__ float tanh_f(float x) { return 1.0f - 2.0f / (__expf(2.0f * x) + 1.0f); }

// DPP quad_perm lane swaps (VALU pipe): xor1 = [1,0,3,2] = 0xB1, xor2 = [2,3,0,1] = 0x4E
__device__ __forceinline__ float dpp_xor1(float x) {
  return __int_as_float(__builtin_amdgcn_mov_dpp(__float_as_int(x), 0xB1, 0xF, 0xF, true));
}
__device__ __forceinline__ float dpp_xor2(float x) {
  return __int_as_float(__builtin_amdgcn_mov_dpp(__float_as_int(x), 0x4E, 0xF, 0xF, true));
}

// Reduce-scatter of 8 per-lane partials: lane (b2 b1 b0 = low bits) ends up
// holding the full wave-sum of v[4*b0 + 2*b1 + b2]. 4 ds shuffles + 6 DPP.
__device__ __forceinline__ float reduce8_scatter(const float v[8], int lane) {
  const bool c0 = lane & 1, c1 = lane & 2, c2 = lane & 4;
  float w[4];
#pragma unroll
  for (int k = 0; k < 4; ++k) {
    float mine = c0 ? v[4 + k] : v[k];
    float send = c0 ? v[k] : v[4 + k];
    w[k] = mine + dpp_xor1(send);
  }
  float u[2];
#pragma unroll
  for (int k = 0; k < 2; ++k) {
    float mine = c1 ? w[2 + k] : w[k];
    float send = c1 ? w[k] : w[2 + k];
    u[k] = mine + dpp_xor2(send);
  }
  float mine = c2 ? u[1] : u[0];
  float send = c2 ? u[0] : u[1];
  float z = mine + __shfl_xor(send, 4, 64);
  z += __shfl_xor(z, 8, 64);
  z += __shfl_xor(z, 16, 64);
  z += __shfl_xor(z, 32, 64);
  return z;
}

// Prepass: Qx[t*B+b][w] = sum_d X[t][b][d] * Wq[w][d] + bq[w]  (x-part, dims 0..127).
// One wave per (t,b); 65536 blocks; memory-bound (~8 us).
__global__ __launch_bounds__(64) void qx_prepass(
    const float* __restrict__ X, const float* __restrict__ Wq,
    const float* __restrict__ bq, float* __restrict__ Qx)
{
  const int lane = threadIdx.x;
  const int tb   = blockIdx.x;
  const float* xp = X + (size_t)tb * IN_DIM;
  float x0 = xp[lane], x1 = xp[lane + 64];
  float v[8];
#pragma unroll
  for (int w = 0; w < 8; ++w)
    v[w] = x0 * Wq[w * 256 + lane] + x1 * Wq[w * 256 + 64 + lane];
  float z = reduce8_scatter(v, lane);
  const int w_own = 4 * (lane & 1) + 2 * ((lane >> 1) & 1) + ((lane >> 2) & 1);
  if (lane < 8) Qx[(size_t)tb * 8 + w_own] = z + bq[w_own];
}

// One block per batch element; wave wv handles gate wv (f,i,g,o).
// Quantum circuit: exact 4-dim transfer-matrix recursion (validated R4):
//   state (u,d,P,R); per wire: K=cos(b0)cos(q), A2=sin(b0)cos(q), B2=sin(q),
//   C=cos(b1), S=sin(b1):
//     Mu=K*u-B2*R; Md=d+A2*P; MP=A2*d+P; MR=B2*u+K*R
//     u'=C*Md; d'=C*Mu; P'=-S*MP; R'=-S*MR   (u/d swap)
//   ev[w-1]=Md (consumed by fused gate GEMM immediately); ev[7]=d_7+P_7.
__global__ __launch_bounds__(256) void qlstm_kernel(
    const float* __restrict__ Qx, const float* __restrict__ Wq,
    const float* __restrict__ pf, const float* __restrict__ pi_, const float* __restrict__ pg,
    const float* __restrict__ po, const float* __restrict__ Wf, const float* __restrict__ bf,
    const float* __restrict__ Wi, const float* __restrict__ bi, const float* __restrict__ Wg,
    const float* __restrict__ bg, const float* __restrict__ Wo, const float* __restrict__ bo,
    float* __restrict__ out)
{
  __shared__ float gsh[2][128 * 6];          // gates pad-6, dbuf by t&1
  __shared__ __align__(16) float qs[4][16];  // per-wave (c,s)x8 broadcast (in-wave only)

  const int tid  = threadIdx.x;
  const int lane = tid & 63;
  const int wv   = tid >> 6;
  const int b    = blockIdx.x;

  const float* gW = (wv == 0) ? Wf : (wv == 1) ? Wi : (wv == 2) ? Wg : Wo;
  const float* gB = (wv == 0) ? bf : (wv == 1) ? bi : (wv == 2) ? bg : bo;
  const float* gP = (wv == 0) ? pf : (wv == 1) ? pi_ : (wv == 2) ? pg : po;

  // ---- one-time register preloads ----
  // Wq h-part (dims 128..255), rows 0..7, packed over wire pairs (2p, 2p+1)
  vf2 wh2[4][2];
#pragma unroll
  for (int p = 0; p < 4; ++p)
#pragma unroll
    for (int k = 0; k < 2; ++k) {
      wh2[p][k].x = Wq[(2 * p)     * 256 + 128 + lane + 64 * k];
      wh2[p][k].y = Wq[(2 * p + 1) * 256 + 128 + lane + 64 * k];
    }

  // wire owned by this lane after reduce8_scatter: w_own = 4b0 + 2b1 + b2
  const int w_own = 4 * (lane & 1) + 2 * ((lane >> 1) & 1) + ((lane >> 2) & 1);

  // gate weights packed over the two h's this lane owns: (h=lane, h=lane+64)
  vf2 wg2[8];
#pragma unroll
  for (int w = 0; w < 8; ++w) {
    wg2[w].x = gW[lane * 8 + w];
    wg2[w].y = gW[(lane + 64) * 8 + w];
  }
  vf2 br2v; br2v.x = gB[lane]; br2v.y = gB[lane + 64];

  // TM per-wire constants (FULL angles, t-invariant); (cb0,sb0) packed
  vf2 cbsb[8];
  float C1[8], S1[8];
#pragma unroll
  for (int w = 0; w < 8; ++w) {
    float th0 = gP[w], th1 = gP[8 + w];
    cbsb[w].x = cosf(th0); cbsb[w].y = sinf(th0);
    C1[w] = cosf(th1); S1[w] = sinf(th1);
  }

  float c0r = 0.0f, c1r = 0.0f, h0r = 0.0f, h1r = 0.0f;

  // Qx prefetch (owner lanes only; lanes 0..7 cover wires {0,4,2,6,1,5,3,7})
  float nqx = 0.0f;
  if (lane < 8) nqx = Qx[(size_t)b * 8 + w_own];

#pragma unroll 1
  for (int t = 0; t < SEQ; ++t) {
    float qxv = nqx;
    if (t + 1 < SEQ && lane < 8)
      nqx = Qx[((size_t)(t + 1) * BATCH + b) * 8 + w_own];

    // ---- q_in = Qx (precomputed) + Wh.h ; reduce-scatter; owner sincos ----
    vf2 qp2[4];
#pragma unroll
    for (int p = 0; p < 4; ++p)
      qp2[p] = h0r * wh2[p][0] + h1r * wh2[p][1];
    float v[8];
#pragma unroll
    for (int p = 0; p < 4; ++p) { v[2 * p] = qp2[p].x; v[2 * p + 1] = qp2[p].y; }
    float z = reduce8_scatter(v, lane) + qxv;   // bq folded into Qx
    float sz, cz;
    __sincosf(z, &sz, &cz);                     // FULL angle: TM needs cos q, sin q

    // in-wave LDS broadcast: owners write (c,s), all lanes read 4x b128.
    // Same-wave DS ops are in-order -> no barrier needed.
    if (lane < 8) {
      qs[wv][2 * w_own]     = cz;
      qs[wv][2 * w_own + 1] = sz;
    }
    float cq[8], sq[8];
    {
      const float4* q4 = (const float4*)&qs[wv][0];
      float4 r0 = q4[0], r1 = q4[1], r2 = q4[2], r3 = q4[3];
      cq[0] = r0.x; sq[0] = r0.y; cq[1] = r0.z; sq[1] = r0.w;
      cq[2] = r1.x; sq[2] = r1.y; cq[3] = r1.z; sq[3] = r1.w;
      cq[4] = r2.x; sq[4] = r2.y; cq[5] = r2.z; sq[5] = r2.w;
      cq[6] = r3.x; sq[6] = r3.y; cq[7] = r3.z; sq[7] = r3.w;
    }

    // ---- transfer-matrix chain with FUSED gate GEMM ----
    vf2 acc = br2v;
    float u, d, P, R;
    {
      vf2 KA0 = cbsb[0] * cq[0];      // (K0, A2_0) pk_mul
      u = C1[0];
      d = C1[0] * KA0.x;
      P = -S1[0] * KA0.y;
      R = -S1[0] * sq[0];
    }
#pragma unroll
    for (int w = 1; w < 8; ++w) {
      vf2 KA = cbsb[w] * cq[w];       // (K, A2) pk_mul
      float K = KA.x, A2 = KA.y, B2 = sq[w];
      float Md = fmaf(A2, P, d);      // == ev[w-1]
      float MP = fmaf(A2, d, P);
      float Mu = fmaf(K, u, -(B2 * R));
      float MR = fmaf(B2, u, K * R);
      acc = acc + Md * wg2[w - 1];    // fused GEMM (pk_fma)
      vf2 ud2; ud2.x = Md; ud2.y = Mu;
      vf2 PR2; PR2.x = MP; PR2.y = MR;
      ud2 = C1[w] * ud2;              // (u', d') pk_mul
      PR2 = -S1[w] * PR2;             // (P', R') pk_mul
      u = ud2.x; d = ud2.y; P = PR2.x; R = PR2.y;
    }
    float ev7 = d + P;                // last site: full sum
    acc = acc + ev7 * wg2[7];

    // ---- activation + gate exchange ----
    float* gbuf = gsh[t & 1];
    float g0 = (wv == 2) ? tanh_f(acc.x) : sigmoid_f(acc.x);
    float g1 = (wv == 2) ? tanh_f(acc.y) : sigmoid_f(acc.y);
    gbuf[lane * 6 + wv] = g0;
    gbuf[(lane + 64) * 6 + wv] = g1;
    __syncthreads();

    // ---- LSTM cell update, replicated in every wave (h,c stay in regs) ----
    float2 fi0 = *(const float2*)&gbuf[lane * 6];
    float2 go0 = *(const float2*)&gbuf[lane * 6 + 2];
    float2 fi1 = *(const float2*)&gbuf[(lane + 64) * 6];
    float2 go1 = *(const float2*)&gbuf[(lane + 64) * 6 + 2];
    c0r = fi0.x * c0r + fi0.y * go0.x;
    c1r = fi1.x * c1r + fi1.y * go1.x;
    h0r = go0.y * tanh_f(c0r);
    h1r = go1.y * tanh_f(c1r);

    if (wv == 0) {
      float* op = out + ((size_t)t * BATCH + b) * HID;
      op[lane] = h0r; op[lane + 64] = h1r;
    }
  }

  if (wv == 0) {
    size_t base = (size_t)SEQ * BATCH * HID;
    out[base + (size_t)b * HID + lane] = h0r;
    out[base + (size_t)b * HID + lane + 64] = h1r;
    out[base + (size_t)BATCH * HID + (size_t)b * HID + lane] = c0r;
    out[base + (size_t)BATCH * HID + (size_t)b * HID + lane + 64] = c1r;
  }
}

extern "C" void kernel_launch(void* const* d_in, const int* in_sizes, int n_in,
                              void* d_out, int out_size, void* d_ws, size_t ws_size,
                              hipStream_t stream) {
  (void)in_sizes; (void)n_in; (void)out_size; (void)ws_size;
  const float* X   = (const float*)d_in[0];
  const float* Wq  = (const float*)d_in[1];
  const float* bq  = (const float*)d_in[2];
  const float* pf  = (const float*)d_in[3];
  const float* pi_ = (const float*)d_in[4];
  const float* pg  = (const float*)d_in[5];
  const float* po  = (const float*)d_in[6];
  const float* Wf  = (const float*)d_in[7];
  const float* bf  = (const float*)d_in[8];
  const float* Wi  = (const float*)d_in[9];
  const float* bi  = (const float*)d_in[10];
  const float* Wg  = (const float*)d_in[11];
  const float* bg  = (const float*)d_in[12];
  const float* Wo  = (const float*)d_in[13];
  const float* bo  = (const float*)d_in[14];
  float* out = (float*)d_out;
  float* Qx  = (float*)d_ws;                 // SEQ*BATCH*8 floats = 2 MB

  qx_prepass<<<SEQ * BATCH, 64, 0, stream>>>(X, Wq, bq, Qx);
  qlstm_kernel<<<BATCH, 256, 0, stream>>>(Qx, Wq, pf, pi_, pg, po,
                                          Wf, bf, Wi, bi, Wg, bg, Wo, bo, out);
}

// Round 7
// 236.168 us; speedup vs baseline: 1.1070x; 1.1070x over previous
//
#include <hip/hip_runtime.h>

#define SEQ 128
#define BATCH 512
#define IN_DIM 128
#define HID 128

typedef float vf2 __attribute__((ext_vector_type(2)));

__device__ __forceinline__ float tanh_f(float x) { return 1.0f - 2.0f / (__expf(2.0f * x) + 1.0f); }

// Sum over each 8-lane row: quad_perm xor1 (0xB1), xor2 (0x4E), row_half_mirror (0x141).
// All VALU-pipe DPP; every lane of the row ends with the row total.
__device__ __forceinline__ float row8_allsum(float s) {
  s += __int_as_float(__builtin_amdgcn_mov_dpp(__float_as_int(s), 0xB1, 0xF, 0xF, true));
  s += __int_as_float(__builtin_amdgcn_mov_dpp(__float_as_int(s), 0x4E, 0xF, 0xF, true));
  s += __int_as_float(__builtin_amdgcn_mov_dpp(__float_as_int(s), 0x141, 0xF, 0xF, true));
  return s;
}

// Prepass: Qx[tb][w] = sum_{d<128} X[tb][d]*Wq[w][d] + bq[w].
// Lane 8r+c: wire r, dims 16c..16c+15; row-DPP reduce; c==0 writes.
__global__ __launch_bounds__(256) void qx_prepass(
    const float* __restrict__ X, const float* __restrict__ Wq,
    const float* __restrict__ bq, float* __restrict__ Qx)
{
  const int lane = threadIdx.x & 63;
  const int wv   = threadIdx.x >> 6;
  const int tb   = blockIdx.x * 4 + wv;
  const int r = lane >> 3, c = lane & 7;
  const float4* xp = (const float4*)(X + (size_t)tb * IN_DIM + 16 * c);
  const float4* wp = (const float4*)(Wq + r * 256 + 16 * c);
  float4 x0 = xp[0], x1 = xp[1], x2 = xp[2], x3 = xp[3];
  float4 w0 = wp[0], w1 = wp[1], w2 = wp[2], w3 = wp[3];
  float s = x0.x*w0.x + x0.y*w0.y + x0.z*w0.z + x0.w*w0.w
          + x1.x*w1.x + x1.y*w1.y + x1.z*w1.z + x1.w*w1.w
          + x2.x*w2.x + x2.y*w2.y + x2.z*w2.z + x2.w*w2.w
          + x3.x*w3.x + x3.y*w3.y + x3.z*w3.z + x3.w*w3.w;
  s = row8_allsum(s);
  if (c == 0) Qx[(size_t)tb * 8 + r] = s + bq[r];
}

// ONE WAVE per batch element. No barriers anywhere (in-wave ds ordering).
// Lane roles: (r = lane>>3, c = lane&7) for q_in wire r / dims 16c..16c+15;
//             (g = lane>>4, p = lane&15) for gate g, h-outputs 8p..8p+7.
// TM recursion (validated R4) runs with per-lane gate constants: one
// instruction stream = all 4 gates simultaneously.
__global__ __launch_bounds__(64) void qlstm_kernel(
    const float* __restrict__ Qx, const float* __restrict__ Wq,
    const float* __restrict__ pf, const float* __restrict__ pi_, const float* __restrict__ pg,
    const float* __restrict__ po, const float* __restrict__ Wf, const float* __restrict__ bf,
    const float* __restrict__ Wi, const float* __restrict__ bi, const float* __restrict__ Wg,
    const float* __restrict__ bg, const float* __restrict__ Wo, const float* __restrict__ bo,
    float* __restrict__ out)
{
  __shared__ float h_sh[128];
  __shared__ float gsh[512];                 // [gate][128]
  __shared__ __align__(16) float qs[16];     // (c,s) x 8 wires

  const int lane = threadIdx.x;
  const int r = lane >> 3, c = lane & 7;
  const int g = lane >> 4, p = lane & 15;
  const int b = blockIdx.x;

  const float* gW = (g == 0) ? Wf : (g == 1) ? Wi : (g == 2) ? Wg : Wo;
  const float* gB = (g == 0) ? bf : (g == 1) ? bi : (g == 2) ? bg : bo;
  const float* gP = (g == 0) ? pf : (g == 1) ? pi_ : (g == 2) ? pg : po;

  // ---- one-time register preloads ----
  // Wq h-part for wire r, dims 16c..16c+15, as 8 vf2
  vf2 wh[8];
  {
    const vf2* whp = (const vf2*)(Wq + r * 256 + 128 + 16 * c);
#pragma unroll
    for (int k = 0; k < 8; ++k) wh[k] = whp[k];
  }
  // gate-GEMM weights: this lane covers gate g, h = 8p..8p+7 (pairs as vf2)
  vf2 wg2[8][4];
#pragma unroll
  for (int w = 0; w < 8; ++w)
#pragma unroll
    for (int j = 0; j < 4; ++j) {
      wg2[w][j].x = gW[(8 * p + 2 * j)     * 8 + w];
      wg2[w][j].y = gW[(8 * p + 2 * j + 1) * 8 + w];
    }
  vf2 bias2[4];
#pragma unroll
  for (int j = 0; j < 4; ++j) {
    bias2[j].x = gB[8 * p + 2 * j];
    bias2[j].y = gB[8 * p + 2 * j + 1];
  }
  // TM constants for THIS lane's gate
  vf2 cbsb[8];
  float C1[8], S1[8];
#pragma unroll
  for (int w = 0; w < 8; ++w) {
    float th0 = gP[w], th1 = gP[8 + w];
    cbsb[w].x = cosf(th0); cbsb[w].y = sinf(th0);
    C1[w] = cosf(th1); S1[w] = sinf(th1);
  }
  const float amul = (g == 2) ? 2.0f : 1.0f;   // tanh = 2*sigmoid(2x)-1
  const float oadd = (g == 2) ? -1.0f : 0.0f;

  // init state
  h_sh[lane] = 0.0f; h_sh[lane + 64] = 0.0f;
  float c0r = 0.0f, c1r = 0.0f;

  // Qx prefetch (lane's wire r)
  float nqx = Qx[(size_t)b * 8 + r];

#pragma unroll 1
  for (int t = 0; t < SEQ; ++t) {
    float qxv = nqx;
    if (t + 1 < SEQ) nqx = Qx[((size_t)(t + 1) * BATCH + b) * 8 + r];

    // ---- q_in: read h (prev t), partial dot, 3-DPP row reduce, sincos ----
    float s;
    {
      const float4* hp = (const float4*)(h_sh + 16 * c);
      float4 a0 = hp[0], a1 = hp[1], a2 = hp[2], a3 = hp[3];
      vf2 aq;
      aq = wh[0] * (vf2){a0.x, a0.y} + wh[1] * (vf2){a0.z, a0.w}
         + wh[2] * (vf2){a1.x, a1.y} + wh[3] * (vf2){a1.z, a1.w}
         + wh[4] * (vf2){a2.x, a2.y} + wh[5] * (vf2){a2.z, a2.w}
         + wh[6] * (vf2){a3.x, a3.y} + wh[7] * (vf2){a3.z, a3.w};
      s = aq.x + aq.y;
    }
    float z = row8_allsum(s) + qxv;
    float sz, cz;
    __sincosf(z, &sz, &cz);

    // ---- broadcast (c,s) of all 8 wires to every lane (in-wave LDS) ----
    if (c == 0) {
      qs[2 * r]     = cz;
      qs[2 * r + 1] = sz;
    }
    float cq[8], sq[8];
    {
      const float4* q4 = (const float4*)qs;
      float4 q0 = q4[0], q1 = q4[1], q2 = q4[2], q3 = q4[3];
      cq[0] = q0.x; sq[0] = q0.y; cq[1] = q0.z; sq[1] = q0.w;
      cq[2] = q1.x; sq[2] = q1.y; cq[3] = q1.z; sq[3] = q1.w;
      cq[4] = q2.x; sq[4] = q2.y; cq[5] = q2.z; sq[5] = q2.w;
      cq[6] = q3.x; sq[6] = q3.y; cq[7] = q3.z; sq[7] = q3.w;
    }

    // ---- TM chain (per-lane gate constants) with FUSED gate GEMM ----
    vf2 acc0 = bias2[0], acc1 = bias2[1], acc2 = bias2[2], acc3 = bias2[3];
    float u, d, P, R;
    {
      vf2 KA0 = cbsb[0] * cq[0];
      u = C1[0];
      d = C1[0] * KA0.x;
      P = -S1[0] * KA0.y;
      R = -S1[0] * sq[0];
    }
#pragma unroll
    for (int w = 1; w < 8; ++w) {
      vf2 KA = cbsb[w] * cq[w];
      float K = KA.x, A2 = KA.y, B2 = sq[w];
      float Md = fmaf(A2, P, d);            // == ev[w-1]
      float MP = fmaf(A2, d, P);
      float Mu = fmaf(K, u, -(B2 * R));
      float MR = fmaf(B2, u, K * R);
      acc0 = acc0 + Md * wg2[w - 1][0];
      acc1 = acc1 + Md * wg2[w - 1][1];
      acc2 = acc2 + Md * wg2[w - 1][2];
      acc3 = acc3 + Md * wg2[w - 1][3];
      vf2 ud2; ud2.x = Md; ud2.y = Mu;
      vf2 PR2; PR2.x = MP; PR2.y = MR;
      ud2 = C1[w] * ud2;
      PR2 = -S1[w] * PR2;
      u = ud2.x; d = ud2.y; P = PR2.x; R = PR2.y;
    }
    float ev7 = d + P;
    acc0 = acc0 + ev7 * wg2[7][0];
    acc1 = acc1 + ev7 * wg2[7][1];
    acc2 = acc2 + ev7 * wg2[7][2];
    acc3 = acc3 + ev7 * wg2[7][3];

    // ---- activation (branch-free: sigmoid or tanh via amul/oadd) ----
    float av[8] = {acc0.x, acc0.y, acc1.x, acc1.y, acc2.x, acc2.y, acc3.x, acc3.y};
    float o8[8];
#pragma unroll
    for (int k = 0; k < 8; ++k) {
      float e = __expf(-amul * av[k]);
      float sg = 1.0f / (1.0f + e);
      o8[k] = fmaf(sg, amul, oadd);
    }
    {
      float4* gp4 = (float4*)(gsh + g * 128 + 8 * p);
      float4 w0; w0.x = o8[0]; w0.y = o8[1]; w0.z = o8[2]; w0.w = o8[3];
      float4 w1; w1.x = o8[4]; w1.y = o8[5]; w1.z = o8[6]; w1.w = o8[7];
      gp4[0] = w0; gp4[1] = w1;
    }

    // ---- LSTM cell update: lane owns h[lane], h[lane+64] ----
    float f0  = gsh[lane],        f1  = gsh[lane + 64];
    float i0  = gsh[128 + lane],  i1  = gsh[128 + lane + 64];
    float g0v = gsh[256 + lane],  g1v = gsh[256 + lane + 64];
    float oo0 = gsh[384 + lane],  oo1 = gsh[384 + lane + 64];
    c0r = fmaf(f0, c0r, i0 * g0v);
    c1r = fmaf(f1, c1r, i1 * g1v);
    float h0 = oo0 * tanh_f(c0r);
    float h1 = oo1 * tanh_f(c1r);
    h_sh[lane] = h0; h_sh[lane + 64] = h1;

    float* op = out + ((size_t)t * BATCH + b) * HID;
    op[lane] = h0; op[lane + 64] = h1;
  }

  // hx, cx
  {
    size_t base = (size_t)SEQ * BATCH * HID;
    float h0 = h_sh[lane], h1 = h_sh[lane + 64];
    out[base + (size_t)b * HID + lane] = h0;
    out[base + (size_t)b * HID + lane + 64] = h1;
    out[base + (size_t)BATCH * HID + (size_t)b * HID + lane] = c0r;
    out[base + (size_t)BATCH * HID + (size_t)b * HID + lane + 64] = c1r;
  }
}

extern "C" void kernel_launch(void* const* d_in, const int* in_sizes, int n_in,
                              void* d_out, int out_size, void* d_ws, size_t ws_size,
                              hipStream_t stream) {
  (void)in_sizes; (void)n_in; (void)out_size; (void)ws_size;
  const float* X   = (const float*)d_in[0];
  const float* Wq  = (const float*)d_in[1];
  const float* bq  = (const float*)d_in[2];
  const float* pf  = (const float*)d_in[3];
  const float* pi_ = (const float*)d_in[4];
  const float* pg  = (const float*)d_in[5];
  const float* po  = (const float*)d_in[6];
  const float* Wf  = (const float*)d_in[7];
  const float* bf  = (const float*)d_in[8];
  const float* Wi  = (const float*)d_in[9];
  const float* bi  = (const float*)d_in[10];
  const float* Wg  = (const float*)d_in[11];
  const float* bg  = (const float*)d_in[12];
  const float* Wo  = (const float*)d_in[13];
  const float* bo  = (const float*)d_in[14];
  float* out = (float*)d_out;
  float* Qx  = (float*)d_ws;                 // SEQ*BATCH*8 floats = 2 MB

  qx_prepass<<<(SEQ * BATCH) / 4, 256, 0, stream>>>(X, Wq, bq, Qx);
  qlstm_kernel<<<BATCH, 64, 0, stream>>>(Qx, Wq, pf, pi_, pg, po,
                                         Wf, bf, Wi, bi, Wg, bg, Wo, bo, out);
}